// Round 7
// baseline (110.845 us; speedup 1.0000x reference)
//
#include <hip/hip_runtime.h>
#include <hip/hip_bf16.h>
#include <stdint.h>

typedef float f32x4 __attribute__((ext_vector_type(4)));
typedef short bf16x8 __attribute__((ext_vector_type(8)));
typedef unsigned short u16x8 __attribute__((ext_vector_type(8)));

static __device__ __forceinline__ ushort f2bf(float f) {
    union { __hip_bfloat16 h; ushort u; } cv;
    cv.h = __float2bfloat16(f);
    return cv.u;
}
static __device__ __forceinline__ float bf2f(ushort u) {
    union { ushort u; __hip_bfloat16 h; } cv;
    cv.u = u;
    return __bfloat162float(cv.h);
}

static __device__ __forceinline__ void gload_lds16(const void* g, void* l) {
    __builtin_amdgcn_global_load_lds(
        (const __attribute__((address_space(1))) unsigned int*)g,
        (__attribute__((address_space(3))) unsigned int*)l,
        16, 0, 0);
}

// ---- shared GEMM body: C = A @ B^T partials (bf16 out), tile 128x128, BK=64, split-K=4.
// AM/BM: 0 = bf16 operand (global_load_lds, pre-swizzled source),
//        1 = f32 operand (reg-stage: 2x dwordx4 -> cvt -> swizzled ds_write_b128).
// bid in [0,512) = 4(M) x 32(N) x 4(zk), XCD-aware: bid%8 owns 4 consecutive N-tiles.
template<int AM, int BM>
static __device__ __forceinline__
void gemm_body(const void* __restrict__ Ap, const void* __restrict__ Bp,
               ushort* __restrict__ parts, int M, int N, int K,
               int bid, ushort* lds /* 2*16384 elems */)
{
    const int tid  = threadIdx.x;
    const int lane = tid & 63;
    const int wave = tid >> 6;

    const int s   = bid >> 3;
    const int xt  = s & 3;                  // M-tile (4)
    const int yl  = (s >> 2) & 3;
    const int zk  = s >> 4;                 // split-K quarter (4)
    const int yt  = (bid & 7) * 4 + yl;     // N-tile (32)
    const int row0 = xt * 128;
    const int col0 = yt * 128;
    const int Ksub = K >> 2;
    const int koff = zk * Ksub;

    const ushort* A16 = (const ushort*)Ap;
    const float*  A32 = (const float*)Ap;
    const ushort* B16 = (const ushort*)Bp;
    const float*  B32 = (const float*)Bp;

    size_t aoff[4], boff[4];
    int adst[4] = {}, bdst[4] = {};
    #pragma unroll
    for (int c = 0; c < 4; ++c) {
        const int q   = c * 256 + tid;
        const int row = q >> 3;                  // 0..127
        const int cc  = q & 7;                   // chunk within row
        const int cs  = cc ^ (row & 7);          // swizzled slot
        if constexpr (AM == 0) {
            aoff[c] = (size_t)(row0 + row) * K + koff + cs * 8;
        } else {
            aoff[c] = (size_t)(row0 + row) * K + koff + cc * 8;
            adst[c] = row * 64 + cs * 8;
        }
        if constexpr (BM == 0) {
            boff[c] = (size_t)(col0 + row) * K + koff + cs * 8;
        } else {
            boff[c] = (size_t)(col0 + row) * K + koff + cc * 8;
            bdst[c] = row * 64 + cs * 8;
        }
    }

    const int wr = (wave >> 1) * 64;
    const int wc = (wave & 1) * 64;
    const int rA = lane & 15;
    const int kq = lane >> 4;
    const int so0 = (kq ^ (rA & 7)) * 8;

    f32x4 pa[8], pb[8];
    f32x4 acc[4][4] = {};
    const int nk = Ksub >> 6;
    int cur = 0;

    #pragma unroll
    for (int c = 0; c < 4; ++c) {
        if constexpr (AM == 0)
            gload_lds16(A16 + aoff[c], &lds[(c * 256 + wave * 64) * 8]);
        else {
            pa[2 * c]     = *(const f32x4*)(A32 + aoff[c]);
            pa[2 * c + 1] = *(const f32x4*)(A32 + aoff[c] + 4);
        }
        if constexpr (BM == 0)
            gload_lds16(B16 + boff[c], &lds[8192 + (c * 256 + wave * 64) * 8]);
        else {
            pb[2 * c]     = *(const f32x4*)(B32 + boff[c]);
            pb[2 * c + 1] = *(const f32x4*)(B32 + boff[c] + 4);
        }
    }
    if constexpr (AM == 1) {
        #pragma unroll
        for (int c = 0; c < 4; ++c) {
            u16x8 h;
            #pragma unroll
            for (int j = 0; j < 4; ++j) { h[j] = f2bf(pa[2*c][j]); h[4+j] = f2bf(pa[2*c+1][j]); }
            *(u16x8*)&lds[adst[c]] = h;
        }
    }
    if constexpr (BM == 1) {
        #pragma unroll
        for (int c = 0; c < 4; ++c) {
            u16x8 h;
            #pragma unroll
            for (int j = 0; j < 4; ++j) { h[j] = f2bf(pb[2*c][j]); h[4+j] = f2bf(pb[2*c+1][j]); }
            *(u16x8*)&lds[8192 + bdst[c]] = h;
        }
    }
    __syncthreads();

    for (int kt = 0; kt < nk; ++kt) {
        const bool more = (kt + 1 < nk);
        if (more) {
            const size_t kadd = (size_t)(kt + 1) * 64;
            #pragma unroll
            for (int c = 0; c < 4; ++c) {
                if constexpr (AM == 0)
                    gload_lds16(A16 + aoff[c] + kadd, &lds[(cur ^ 1) * 16384 + (c * 256 + wave * 64) * 8]);
                else {
                    pa[2 * c]     = *(const f32x4*)(A32 + aoff[c] + kadd);
                    pa[2 * c + 1] = *(const f32x4*)(A32 + aoff[c] + kadd + 4);
                }
                if constexpr (BM == 0)
                    gload_lds16(B16 + boff[c] + kadd, &lds[(cur ^ 1) * 16384 + 8192 + (c * 256 + wave * 64) * 8]);
                else {
                    pb[2 * c]     = *(const f32x4*)(B32 + boff[c] + kadd);
                    pb[2 * c + 1] = *(const f32x4*)(B32 + boff[c] + kadd + 4);
                }
            }
        }
        const ushort* base = lds + cur * 16384;
        #pragma unroll
        for (int kk = 0; kk < 2; ++kk) {
            const int so = so0 ^ (kk * 32);
            bf16x8 a[4], b[4];
            #pragma unroll
            for (int m = 0; m < 4; ++m)
                a[m] = *(const bf16x8*)&base[(wr + m * 16 + rA) * 64 + so];
            #pragma unroll
            for (int n = 0; n < 4; ++n)
                b[n] = *(const bf16x8*)&base[8192 + (wc + n * 16 + rA) * 64 + so];
            #pragma unroll
            for (int m = 0; m < 4; ++m)
                #pragma unroll
                for (int n = 0; n < 4; ++n)
                    acc[m][n] = __builtin_amdgcn_mfma_f32_16x16x32_bf16(a[m], b[n], acc[m][n], 0, 0, 0);
        }
        if (more) {
            if constexpr (AM == 1) {
                #pragma unroll
                for (int c = 0; c < 4; ++c) {
                    u16x8 h;
                    #pragma unroll
                    for (int j = 0; j < 4; ++j) { h[j] = f2bf(pa[2*c][j]); h[4+j] = f2bf(pa[2*c+1][j]); }
                    *(u16x8*)&lds[(cur ^ 1) * 16384 + adst[c]] = h;
                }
            }
            if constexpr (BM == 1) {
                #pragma unroll
                for (int c = 0; c < 4; ++c) {
                    u16x8 h;
                    #pragma unroll
                    for (int j = 0; j < 4; ++j) { h[j] = f2bf(pb[2*c][j]); h[4+j] = f2bf(pb[2*c+1][j]); }
                    *(u16x8*)&lds[(cur ^ 1) * 16384 + 8192 + bdst[c]] = h;
                }
            }
        }
        __syncthreads();
        cur ^= 1;
    }

    ushort* po = parts + (size_t)zk * M * N;
    const int rb = row0 + wr + (lane >> 4) * 4;
    const int cb = col0 + wc + (lane & 15);
    #pragma unroll
    for (int m = 0; m < 4; ++m)
        #pragma unroll
        for (int n = 0; n < 4; ++n)
            #pragma unroll
            for (int j = 0; j < 4; ++j)
                po[(size_t)(rb + m * 16 + j) * N + cb + n * 16] = f2bf(acc[m][n][j]);
}

// ---- W-GEMM: both operands bf16 (z @ Wbf^T)
__global__ __launch_bounds__(256, 2)
void gemm128_bf(const ushort* __restrict__ A, const ushort* __restrict__ B,
                ushort* __restrict__ parts, int M, int N, int K)
{
    __shared__ ushort lds[2][16384];
    gemm_body<0, 0>(A, B, parts, M, N, K, blockIdx.x, &lds[0][0]);
}

// ---- fused: 512 GEMM blocks (bias = x @ U^T, f32 operands) + 512 W-convert blocks.
// Role by (blockIdx>>3)&1 so both roles round-robin across all 8 XCDs.
__global__ __launch_bounds__(256, 2)
void k_bias_convw(const float* __restrict__ x, const float* __restrict__ U,
                  ushort* __restrict__ parts, int M, int N, int K,
                  const float* __restrict__ W, ushort* __restrict__ Wbf, int nW8)
{
    __shared__ ushort lds[2][16384];
    const int i = blockIdx.x;
    const int sub = (i >> 4) * 8 + (i & 7);     // 0..511 within role
    if (((i >> 3) & 1) == 0) {
        gemm_body<1, 1>(x, U, parts, M, N, K, sub, &lds[0][0]);
    } else {
        int idx = sub * 256 + (int)threadIdx.x;
        const int stride = 512 * 256;
        for (; idx < nW8; idx += stride) {
            f32x4 a = ((const f32x4*)W)[2 * idx];
            f32x4 c = ((const f32x4*)W)[2 * idx + 1];
            u16x8 h;
            #pragma unroll
            for (int j = 0; j < 4; ++j) {
                h[j]     = f2bf(a[j]);
                h[4 + j] = f2bf(c[j]);
            }
            ((u16x8*)Wbf)[idx] = h;
        }
    }
}

// combine 4 bf16 split-K partials + epilogue.
// MODE 0: t = sum(p) + bvec[c];  biasf_out = t; zout = bf16(relu(t))
// MODE 1: t = sum(p) + biasf_in; zout = bf16(relu(t))
// MODE 2: t = sum(p) + biasf_in; fout = relu(t)
template<int MODE>
__global__ void k_combine(const ushort* __restrict__ p, const float* __restrict__ biasf_in,
                          const float* __restrict__ bvec, float* __restrict__ biasf_out,
                          ushort* __restrict__ zout, float* __restrict__ fout,
                          int n4, int Ndiv4)
{
    const int i = blockIdx.x * blockDim.x + threadIdx.x;
    if (i >= n4) return;
    f32x4 v;
    if constexpr (MODE == 0) {
        v = ((const f32x4*)bvec)[i % Ndiv4];
    } else {
        v = ((const f32x4*)biasf_in)[i];
    }
    #pragma unroll
    for (int q = 0; q < 4; ++q) {
        ushort4 h = ((const ushort4*)p)[i + q * n4];
        #pragma unroll
        for (int j = 0; j < 4; ++j) v[j] += bf2f(h[j]);
    }
    if constexpr (MODE == 0) {
        ((f32x4*)biasf_out)[i] = v;
        ushort4 h;
        #pragma unroll
        for (int j = 0; j < 4; ++j) h[j] = f2bf(v[j] > 0.f ? v[j] : 0.f);
        ((ushort4*)zout)[i] = h;
    } else if constexpr (MODE == 1) {
        ushort4 h;
        #pragma unroll
        for (int j = 0; j < 4; ++j) h[j] = f2bf(v[j] > 0.f ? v[j] : 0.f);
        ((ushort4*)zout)[i] = h;
    } else {
        f32x4 r;
        #pragma unroll
        for (int j = 0; j < 4; ++j) r[j] = v[j] > 0.f ? v[j] : 0.f;
        ((f32x4*)fout)[i] = r;
    }
}

extern "C" void kernel_launch(void* const* d_in, const int* in_sizes, int n_in,
                              void* d_out, int out_size, void* d_ws, size_t ws_size,
                              hipStream_t stream)
{
    const float* x = (const float*)d_in[0];   // 512 x 3072
    const float* W = (const float*)d_in[1];   // 4096 x 4096
    const float* U = (const float*)d_in[2];   // 4096 x 3072
    const float* b = (const float*)d_in[3];   // 4096
    float* out = (float*)d_out;               // 512 x 4096 f32

    const int Mb = 512, DIN = 3072, D = 4096;

    char* ws = (char*)d_ws;
    size_t off = 0;
    auto take = [&](size_t bytes) {
        void* p = (void*)(ws + off);
        off += (bytes + 255) & ~(size_t)255;
        return p;
    };
    ushort* Wbf   = (ushort*)take((size_t)D * D * 2);        // 33.6 MB
    float*  biasf = (float*)take((size_t)Mb * D * 4);        //  8.4 MB
    ushort* parts = (ushort*)take((size_t)4 * Mb * D * 2);   // 16.8 MB bf16 partials
    ushort* z0    = (ushort*)take((size_t)Mb * D * 2);       //  4.2 MB
    ushort* z1    = (ushort*)take((size_t)Mb * D * 2);       //  4.2 MB

    const int EB = 256;
    const int n4 = Mb * D / 4;           // 524288
    const dim3 cgrid(n4 / EB);           // 2048
    const dim3 ggrid(512);
    const dim3 gblk(256);

    // fused: bias partials = x @ U^T (f32 staged), co-resident W f32->bf16 convert
    k_bias_convw<<<dim3(1024), gblk, 0, stream>>>(x, U, parts, Mb, D, DIN,
                                                  W, Wbf, D * D / 8);
    k_combine<0><<<cgrid, dim3(EB), 0, stream>>>(parts, nullptr, b, biasf, z0, nullptr, n4, D / 4);

    // z1 = relu(bias + W z0)   (all-bf16 gload_lds path)
    gemm128_bf<<<ggrid, gblk, 0, stream>>>(z0, Wbf, parts, Mb, D, D);
    k_combine<1><<<cgrid, dim3(EB), 0, stream>>>(parts, biasf, nullptr, nullptr, z1, nullptr, n4, D / 4);

    // out = relu(bias + W z1), f32
    gemm128_bf<<<ggrid, gblk, 0, stream>>>(z1, Wbf, parts, Mb, D, D);
    k_combine<2><<<cgrid, dim3(EB), 0, stream>>>(parts, biasf, nullptr, nullptr, nullptr, out, n4, D / 4);

    (void)in_sizes; (void)n_in; (void)out_size; (void)ws_size;
}